// Round 9
// baseline (116.153 us; speedup 1.0000x reference)
//
#include <hip/hip_runtime.h>

#define BATCH 16384
#define DIM   512
#define UNITS 1024
// GAMMA = 0.5 folded into epilogue: out = exp(cross - 0.5*xsq - 0.5*musq)

typedef float v16f __attribute__((ext_vector_type(16)));

#define BPITCH 33
#define MFMA_F8(a, b, c) __builtin_amdgcn_mfma_f32_32x32x16_fp8_fp8((a), (b), (c), 0, 0, 0)

static __device__ __forceinline__ int2 cvt8(const float4 f0, const float4 f1) {
    int lo = __builtin_amdgcn_cvt_pk_fp8_f32(f0.x, f0.y, 0, false);
    lo     = __builtin_amdgcn_cvt_pk_fp8_f32(f0.z, f0.w, lo, true);
    int hi = __builtin_amdgcn_cvt_pk_fp8_f32(f1.x, f1.y, 0, false);
    hi     = __builtin_amdgcn_cvt_pk_fp8_f32(f1.z, f1.w, hi, true);
    return make_int2(lo, hi);
}
static __device__ __forceinline__ float dot8(const float4 f0, const float4 f1) {
    return f0.x * f0.x + f0.y * f0.y + f0.z * f0.z + f0.w * f0.w
         + f1.x * f1.x + f1.y * f1.y + f1.z * f1.z + f1.w * f1.w;
}

// prep-B (R0's proven B-path, unchanged): 32 blocks x 256 threads.
// B8f: byte ((ng*32 + kw)*64 + lane)*8 — lane l holds
//   B[kw*16 + (l>>5)*8 + 0..7][ng*32 + (l&31)].  musq on fp32 values.
__global__ __launch_bounds__(256)
void prep_b_kernel(const float* __restrict__ mu, unsigned char* __restrict__ B8f,
                   float* __restrict__ musq) {
    __shared__ __attribute__((aligned(16))) char smem[512 * BPITCH * 4 + 1024];
    float* lds = (float*)smem;                       // [512][BPITCH]
    float* red = (float*)(smem + 512 * BPITCH * 4);  // [32][8]
    const int t  = threadIdx.x;
    const int l  = t & 63, w = t >> 6;
    const int ln = l & 31, h = l >> 5;
    const int nb = blockIdx.x;
    const int n0 = nb * 32;
    const int col = t & 31, kg = t >> 5;
    float s = 0.f;
    for (int i = 0; i < 64; i++) {
        const int k = i * 8 + kg;
        float v = mu[(size_t)k * UNITS + n0 + col];
        s += v * v;
        lds[k * BPITCH + col] = v;
    }
    red[col * 8 + kg] = s;
    __syncthreads();
    if (t < 32) {
        float a = 0.f;
#pragma unroll
        for (int i = 0; i < 8; i++) a += red[t * 8 + i];
        musq[n0 + t] = a;
    }
#pragma unroll
    for (int j = 0; j < 8; j++) {
        const int kw = w * 8 + j;
        const float* p = lds + (kw * 16 + h * 8) * BPITCH + ln;
        float f[8];
#pragma unroll
        for (int i = 0; i < 8; i++) f[i] = p[i * BPITCH];
        *(int2*)(B8f + (((size_t)nb * 32 + kw) * 64 + l) * 8) =
            cvt8(make_float4(f[0], f[1], f[2], f[3]),
                 make_float4(f[4], f[5], f[6], f[7]));
    }
}

// Main RBF kernel v2: 512 blocks x 512 threads (8 waves), 52.5 KB LDS ->
// 2 blocks/CU. Block tile 32M x 1024N — A is block-private in LDS (same as
// R8, no global A round-trip); halving the block lets a co-resident sibling
// overlap its K/store phase with this block's A-staging phase (the ~7 µs of
// per-CU dead store time that capped R8's 1-block/CU layout).
//  Stage: two 16-row halves: coalesced float4 -> stage[16][516], barrier,
//    convert (thread t: row t&15, h (t>>4)&1, kw t>>5 and kw+16 -> 2 octets)
//    into Afrag fragments + dot8 partials -> red; barrier.
//  xsq reduced into LDS (never leaves the block).
//  K-loop per wave (wave w = cols [w*128,+128)): TWO 64-col passes of
//    {32 kw x (1 ds_read A + 2 global B8f + 2 MFMA)} + exp/NT-store epilogue
//    per pass. No barriers after staging; waves drift. B8f L2-resident.
__global__ __launch_bounds__(512, 4)
void rbf_main_kernel(const float* __restrict__ in,
                     const unsigned char* __restrict__ B8f,
                     const float* __restrict__ musq,
                     float* __restrict__ out) {
    // LDS: stage 33024 | Afrag 16384 | red 4224 | xsq_l 128 = 53760 B
    __shared__ __attribute__((aligned(16))) unsigned char smem[53760];
    float* stage = (float*)smem;                         // [16][516] fp32
    unsigned char* Afrag = smem + 33024;                 // [32 kw][64 l][8]
    float* red   = (float*)(smem + 49408);               // [32][33]
    float* xsq_l = (float*)(smem + 53632);               // [32]

    const int t  = threadIdx.x;
    const int l  = t & 63;
    const int w  = t >> 6;          // wave 0..7 = 128-col group
    const int ln = l & 31;
    const int h  = l >> 5;
    const int m0 = blockIdx.x * 32; // this block's 32 A-rows

    // ---- Stage + convert two 16-row halves ----
#pragma unroll
    for (int s = 0; s < 2; s++) {
        const float4* src = (const float4*)(in + (size_t)(m0 + s * 16) * DIM);
        float4* s4 = (float4*)stage;
#pragma unroll
        for (int i = 0; i < 4; i++) {
            const int f = i * 512 + t;                   // float4 id 0..2047
            s4[(f >> 7) * 129 + (f & 127)] = src[f];
        }
        __syncthreads();
        // convert: thread t covers (row t&15, h (t>>4)&1, kw {t>>5, t>>5+16})
        const int row  = t & 15;
        const int slot = t >> 4;                         // 0..31
        const int hh   = slot & 1, kw = slot >> 1;       // kw 0..15
        const int rg   = s * 16 + row;                   // global row 0..31
        const float* p = stage + row * 516 + kw * 16 + hh * 8;
        float4 a0 = *(const float4*)p;
        float4 a1 = *(const float4*)(p + 4);
        float4 b0 = *(const float4*)(p + 256);           // kw+16
        float4 b1 = *(const float4*)(p + 260);
        red[rg * 33 + slot] = dot8(a0, a1) + dot8(b0, b1);
        *(int2*)(Afrag + ((kw * 64) + hh * 32 + rg) * 8)        = cvt8(a0, a1);
        *(int2*)(Afrag + (((kw + 16) * 64) + hh * 32 + rg) * 8) = cvt8(b0, b1);
        __syncthreads();
    }
    if (t < 32) {                   // xsq for the 32 rows, stays in LDS
        float a = 0.f;
#pragma unroll
        for (int i = 0; i < 32; i++) a += red[t * 33 + i];
        xsq_l[t] = -0.5f * a;
    }
    __syncthreads();                // last barrier; waves free-run from here

    // ---- Per-wave GEMM: rows [m0,+32) x cols [w*128,+128) ----
    const long* Af = (const long*)Afrag;
    const long* Bg = (const long*)B8f + (size_t)(w * 4) * 2048 + l;

#pragma unroll
    for (int g2 = 0; g2 < 2; g2++) {                     // two 64-col passes
        const long* B0 = Bg + (size_t)(g2 * 2) * 2048;
        const long* B1 = B0 + 2048;

        v16f acc0 = (v16f)0.f, acc1 = (v16f)0.f;
#pragma unroll 8
        for (int kw = 0; kw < 32; kw++) {
            long a  = Af[kw * 64 + l];
            long b0 = B0[kw * 64];
            long b1 = B1[kw * 64];
            acc0 = MFMA_F8(a, b0, acc0);
            acc1 = MFMA_F8(a, b1, acc1);
        }

        // Epilogue. C/D layout: col = l&31, row = (r&3) + 8*(r>>2) + 4*h.
        const int nc0 = w * 128 + g2 * 64;
        const float mb0 = -0.5f * musq[nc0 + ln];
        const float mb1 = -0.5f * musq[nc0 + 32 + ln];
        float* obase = out + nc0 + ln;
#pragma unroll
        for (int r = 0; r < 16; r++) {
            const int rl = (r & 3) + 8 * (r >> 2) + 4 * h;
            const float xb = xsq_l[rl];                  // LDS broadcast
            float* orow = obase + (size_t)(m0 + rl) * UNITS;
            __builtin_nontemporal_store(__expf(acc0[r] + xb + mb0), orow);
            __builtin_nontemporal_store(__expf(acc1[r] + xb + mb1), orow + 32);
        }
    }
}

extern "C" void kernel_launch(void* const* d_in, const int* in_sizes, int n_in,
                              void* d_out, int out_size, void* d_ws, size_t ws_size,
                              hipStream_t stream) {
    const float* inputs = (const float*)d_in[0];   // [16384, 512] fp32
    const float* mu     = (const float*)d_in[1];   // [512, 1024] fp32
    float* out = (float*)d_out;                    // [16384, 1024] fp32

    char* ws = (char*)d_ws;
    unsigned char* B8f = (unsigned char*)ws;                 // 512 KiB
    float* musq = (float*)(ws + (size_t)UNITS * DIM);        // 4 KiB

    prep_b_kernel<<<32, 256, 0, stream>>>(mu, B8f, musq);
    rbf_main_kernel<<<512, 512, 0, stream>>>(inputs, B8f, musq, out);
}

// Round 10
// 105.360 us; speedup vs baseline: 1.1024x; 1.1024x over previous
//
#include <hip/hip_runtime.h>

#define BATCH 16384
#define DIM   512
#define UNITS 1024
// GAMMA = 0.5 folded into epilogue: out = exp(cross - 0.5*xsq - 0.5*musq)

typedef float v16f __attribute__((ext_vector_type(16)));

#define BPITCH 33
#define MFMA_F8(a, b, c) __builtin_amdgcn_mfma_f32_32x32x16_fp8_fp8((a), (b), (c), 0, 0, 0)

static __device__ __forceinline__ int2 cvt8(const float4 f0, const float4 f1) {
    int lo = __builtin_amdgcn_cvt_pk_fp8_f32(f0.x, f0.y, 0, false);
    lo     = __builtin_amdgcn_cvt_pk_fp8_f32(f0.z, f0.w, lo, true);
    int hi = __builtin_amdgcn_cvt_pk_fp8_f32(f1.x, f1.y, 0, false);
    hi     = __builtin_amdgcn_cvt_pk_fp8_f32(f1.z, f1.w, hi, true);
    return make_int2(lo, hi);
}
static __device__ __forceinline__ float dot8(const float4 f0, const float4 f1) {
    return f0.x * f0.x + f0.y * f0.y + f0.z * f0.z + f0.w * f0.w
         + f1.x * f1.x + f1.y * f1.y + f1.z * f1.z + f1.w * f1.w;
}

// prep-B (R0's proven B-path, unchanged): 32 blocks x 256 threads.
// B8f: byte ((ng*32 + kw)*64 + lane)*8 — lane l holds
//   B[kw*16 + (l>>5)*8 + 0..7][ng*32 + (l&31)].  musq on fp32 values.
__global__ __launch_bounds__(256)
void prep_b_kernel(const float* __restrict__ mu, unsigned char* __restrict__ B8f,
                   float* __restrict__ musq) {
    __shared__ __attribute__((aligned(16))) char smem[512 * BPITCH * 4 + 1024];
    float* lds = (float*)smem;                       // [512][BPITCH]
    float* red = (float*)(smem + 512 * BPITCH * 4);  // [32][8]
    const int t  = threadIdx.x;
    const int l  = t & 63, w = t >> 6;
    const int ln = l & 31, h = l >> 5;
    const int nb = blockIdx.x;
    const int n0 = nb * 32;
    const int col = t & 31, kg = t >> 5;
    float s = 0.f;
    for (int i = 0; i < 64; i++) {
        const int k = i * 8 + kg;
        float v = mu[(size_t)k * UNITS + n0 + col];
        s += v * v;
        lds[k * BPITCH + col] = v;
    }
    red[col * 8 + kg] = s;
    __syncthreads();
    if (t < 32) {
        float a = 0.f;
#pragma unroll
        for (int i = 0; i < 8; i++) a += red[t * 8 + i];
        musq[n0 + t] = a;
    }
#pragma unroll
    for (int j = 0; j < 8; j++) {
        const int kw = w * 8 + j;
        const float* p = lds + (kw * 16 + h * 8) * BPITCH + ln;
        float f[8];
#pragma unroll
        for (int i = 0; i < 8; i++) f[i] = p[i * BPITCH];
        *(int2*)(B8f + (((size_t)nb * 32 + kw) * 64 + l) * 8) =
            cvt8(make_float4(f[0], f[1], f[2], f[3]),
                 make_float4(f[4], f[5], f[6], f[7]));
    }
}

// Main RBF kernel v3: R8's proven shell (256 blocks x 1024 threads, 16 waves,
// 1 block/CU, block-private 64 A-rows in LDS) with ONE change: wave tile is
// 64M x 64N as two 64M x 32N passes. Per kw-iter: 2 LDS A-reads + 1 global
// B-load + 2 MFMAs (was 1 A + 2 B + 2 MFMA) -> global B-loads halve and each
// B-load feeds 2 MFMAs (the K-loop is latency-bound on B per R9 counters);
// B8f is now read ONCE per block (L2 B traffic halves to 128 MB). Staging,
// layouts, epilogue mechanics, prep-B: identical to R8.
__global__ __launch_bounds__(1024, 4)
void rbf_main_kernel(const float* __restrict__ in,
                     const unsigned char* __restrict__ B8f,
                     const float* __restrict__ musq,
                     float* __restrict__ out) {
    // LDS: stage 66048 | Afrag 32768 | red 8448 | xsq_l 256  = 107520 B
    __shared__ __attribute__((aligned(16))) unsigned char smem[107520];
    float* stage = (float*)smem;                         // [32][516] fp32
    unsigned char* Afrag = smem + 66048;                 // [2][32 kw][64 l][8]
    float* red   = (float*)(smem + 98816);               // [64][33]
    float* xsq_l = (float*)(smem + 107264);              // [64]

    const int t  = threadIdx.x;
    const int l  = t & 63;
    const int w  = t >> 6;          // wave 0..15 = 64-col group
    const int ln = l & 31;
    const int h  = l >> 5;
    const int m0 = blockIdx.x * 64; // this block's 64 A-rows

    // ---- Stage + convert two 32-row chunks (identical to R8) ----
#pragma unroll
    for (int rc = 0; rc < 2; rc++) {
        const float4* src = (const float4*)(in + (size_t)(m0 + rc * 32) * DIM);
        float4* s4 = (float4*)stage;
#pragma unroll
        for (int i = 0; i < 4; i++) {
            const int f = i * 1024 + t;                  // float4 id 0..4095
            s4[(f >> 7) * 129 + (f & 127)] = src[f];
        }
        __syncthreads();
        // convert: thread covers (row ln, k-half h) x kw = {w*2, w*2+1}
        float s = 0.f;
#pragma unroll
        for (int j = 0; j < 2; j++) {
            const int kw = w * 2 + j;
            const float* p = stage + ln * 516 + kw * 16 + h * 8;
            float4 f0 = *(const float4*)p;
            float4 f1 = *(const float4*)(p + 4);
            s += dot8(f0, f1);
            *(int2*)(Afrag + (((rc * 32 + kw) * 64) + h * 32 + ln) * 8) =
                cvt8(f0, f1);
        }
        red[(rc * 32 + ln) * 33 + w * 2 + h] = s;
        __syncthreads();
    }
    if (t < 64) {                   // xsq for all 64 rows, stays in LDS
        float a = 0.f;
#pragma unroll
        for (int i = 0; i < 32; i++) a += red[t * 33 + i];
        xsq_l[t] = -0.5f * a;
    }
    __syncthreads();                // last barrier; waves free-run from here

    // ---- Per-wave GEMM: rows [m0,+64) x cols [w*64,+64), 2 N-passes ----
    const long* Af0 = (const long*)Afrag;                // row chunk 0
    const long* Af1 = (const long*)(Afrag + 16384);      // row chunk 1
    const long* Bg  = (const long*)B8f + (size_t)(w * 2) * 2048 + l;

#pragma unroll
    for (int g2 = 0; g2 < 2; g2++) {                     // two 32-col passes
        const long* B0 = Bg + (size_t)g2 * 2048;

        v16f acc0 = (v16f)0.f, acc1 = (v16f)0.f;
#pragma unroll 8
        for (int kw = 0; kw < 32; kw++) {
            long a0 = Af0[kw * 64 + l];
            long a1 = Af1[kw * 64 + l];
            long b  = B0[kw * 64];
            acc0 = MFMA_F8(a0, b, acc0);                 // rows m0..m0+31
            acc1 = MFMA_F8(a1, b, acc1);                 // rows m0+32..m0+63
        }

        // Epilogue. C/D layout: col = l&31, row = (r&3) + 8*(r>>2) + 4*h.
        const int nc0 = w * 64 + g2 * 32;
        const float mb = -0.5f * musq[nc0 + ln];
        float* obase = out + nc0 + ln;
#pragma unroll
        for (int r = 0; r < 16; r++) {
            const int rl = (r & 3) + 8 * (r >> 2) + 4 * h;
            const float xb0 = xsq_l[rl];                 // LDS broadcast
            const float xb1 = xsq_l[32 + rl];
            __builtin_nontemporal_store(
                __expf(acc0[r] + xb0 + mb), obase + (size_t)(m0 + rl) * UNITS);
            __builtin_nontemporal_store(
                __expf(acc1[r] + xb1 + mb), obase + (size_t)(m0 + 32 + rl) * UNITS);
        }
    }
}

extern "C" void kernel_launch(void* const* d_in, const int* in_sizes, int n_in,
                              void* d_out, int out_size, void* d_ws, size_t ws_size,
                              hipStream_t stream) {
    const float* inputs = (const float*)d_in[0];   // [16384, 512] fp32
    const float* mu     = (const float*)d_in[1];   // [512, 1024] fp32
    float* out = (float*)d_out;                    // [16384, 1024] fp32

    char* ws = (char*)d_ws;
    unsigned char* B8f = (unsigned char*)ws;                 // 512 KiB
    float* musq = (float*)(ws + (size_t)UNITS * DIM);        // 4 KiB

    prep_b_kernel<<<32, 256, 0, stream>>>(mu, B8f, musq);
    rbf_main_kernel<<<256, 1024, 0, stream>>>(inputs, B8f, musq, out);
}